// Round 8
// baseline (202.563 us; speedup 1.0000x reference)
//
#include <hip/hip_runtime.h>

// Problem constants (match reference)
#define NB 32
#define CH 3
#define HH 768
#define WW 768

// Tiling
#define TW 64                  // tile width
#define TH 32                  // tile height
#define SW 72                  // staged (used) width: [tw0-4, tw0+68)
#define SWP 76                 // LDS row stride (19 granules; swizzle below)
#define SH (TH + 4)            // 36 staged rows
#define CSTRIDE (SH * SWP)
#define TPB 6                  // tiles per block (vertical chain)
#define NTC (WW / TW)          // 12
#define NTG (HH / (TH * TPB))  // 4
#define NWG (NB * NTC * NTG)   // 1536
#define UNITS (SH * (SW / 4))  // 648 float4-units per tile

// Granule swizzle within a row: kills the tx / tx+8 (delta = 32 floats) alias.
__device__ inline int swzg(int g) { return g ^ (((g >> 3) & 1) << 2); }

__global__ __launch_bounds__(256, 4) void colwarp_conv_kernel(
    const float* __restrict__ im,
    const float* __restrict__ flat,
    float* __restrict__ out)
{
    // XCD-contiguous mapping: each XCD owns a contiguous 1/8 of the chains.
    const int d   = blockIdx.x;
    const int wid = (d & 7) * (NWG / 8) + (d >> 3);
    const int tg  = wid & 3;
    const int t2  = wid >> 2;
    const int tc  = t2 % NTC;
    const int b   = t2 / NTC;
    const int tw0 = tc * TW;
    const int thbase = tg * (TPB * TH);

    __shared__ float xs[CH][SH][SWP];   // 32832 B -> 4 blocks/CU

    const int tid = threadIdx.x;

    // ---- per-sample params (b block-uniform -> scalar) ----
    const float* f = flat + b * 37;
    float Wm[3][3];
#pragma unroll
    for (int i = 0; i < 3; ++i)
#pragma unroll
        for (int j = 0; j < 3; ++j) Wm[i][j] = f[i * 3 + j];
    float sh3[3];
#pragma unroll
    for (int i = 0; i < 3; ++i) sh3[i] = f[9 + i];
    float K[5][5];
#pragma unroll
    for (int i = 0; i < 5; ++i)
#pragma unroll
        for (int j = 0; j < 5; ++j) K[i][j] = f[12 + i * 5 + j];
    float bias[3];
#pragma unroll
    for (int c = 0; c < 3; ++c)
        bias[c] = sh3[0]*Wm[0][c] + sh3[1]*Wm[1][c] + sh3[2]*Wm[2][c];

    const size_t plane = (size_t)HH * WW;
    const float* im0 = im + (size_t)b * CH * plane;

    // ---- this thread's staging units: u, u+256, u+512 ----
    int ur[3], uldso[3], ugw[3];
    bool uon[3];
#pragma unroll
    for (int ui = 0; ui < 3; ++ui) {
        const int u  = tid + 256 * ui;
        const int rr = u / (SW / 4);
        const int c4 = u - rr * (SW / 4);
        ur[ui]    = rr;
        uldso[ui] = rr * SWP + swzg(c4) * 4;   // swizzled granule
        ugw[ui]   = tw0 - 4 + c4 * 4;
        uon[ui]   = (u < UNITS);
    }

    float4 v[3][CH];   // in-flight raw loads (issue-early, write-late)
    bool vok[3];

#define STAGE_LOAD(TH0)                                                        \
    _Pragma("unroll")                                                          \
    for (int ui = 0; ui < 3; ++ui) {                                           \
        const int gh = (TH0) + ur[ui] - 2;                                     \
        const bool ok = uon[ui] && ((unsigned)gh < (unsigned)HH)               \
                                && ((unsigned)ugw[ui] < (unsigned)WW);         \
        vok[ui] = ok;                                                          \
        if (ok) {                                                              \
            const size_t off = (size_t)gh * WW + ugw[ui];                      \
            v[ui][0] = *(const float4*)(im0 + off);                            \
            v[ui][1] = *(const float4*)(im0 + plane + off);                    \
            v[ui][2] = *(const float4*)(im0 + 2 * plane + off);                \
        }                                                                      \
    }

#define STAGE_WRITE()                                                          \
    _Pragma("unroll")                                                          \
    for (int ui = 0; ui < 3; ++ui) {                                           \
        if (uon[ui]) {                                                         \
            float4 m0 = make_float4(0.f, 0.f, 0.f, 0.f), m1 = m0, m2 = m0;     \
            if (vok[ui]) {                                                     \
                const float4 a0 = v[ui][0], a1 = v[ui][1], a2 = v[ui][2];      \
                m0.x = a0.x*Wm[0][0] + a1.x*Wm[1][0] + a2.x*Wm[2][0] + bias[0];\
                m0.y = a0.y*Wm[0][0] + a1.y*Wm[1][0] + a2.y*Wm[2][0] + bias[0];\
                m0.z = a0.z*Wm[0][0] + a1.z*Wm[1][0] + a2.z*Wm[2][0] + bias[0];\
                m0.w = a0.w*Wm[0][0] + a1.w*Wm[1][0] + a2.w*Wm[2][0] + bias[0];\
                m1.x = a0.x*Wm[0][1] + a1.x*Wm[1][1] + a2.x*Wm[2][1] + bias[1];\
                m1.y = a0.y*Wm[0][1] + a1.y*Wm[1][1] + a2.y*Wm[2][1] + bias[1];\
                m1.z = a0.z*Wm[0][1] + a1.z*Wm[1][1] + a2.z*Wm[2][1] + bias[1];\
                m1.w = a0.w*Wm[0][1] + a1.w*Wm[1][1] + a2.w*Wm[2][1] + bias[1];\
                m2.x = a0.x*Wm[0][2] + a1.x*Wm[1][2] + a2.x*Wm[2][2] + bias[2];\
                m2.y = a0.y*Wm[0][2] + a1.y*Wm[1][2] + a2.y*Wm[2][2] + bias[2];\
                m2.z = a0.z*Wm[0][2] + a1.z*Wm[1][2] + a2.z*Wm[2][2] + bias[2];\
                m2.w = a0.w*Wm[0][2] + a1.w*Wm[1][2] + a2.w*Wm[2][2] + bias[2];\
            }                                                                  \
            *(float4*)(&xs[0][0][0] + 0 * CSTRIDE + uldso[ui]) = m0;           \
            *(float4*)(&xs[0][0][0] + 1 * CSTRIDE + uldso[ui]) = m1;           \
            *(float4*)(&xs[0][0][0] + 2 * CSTRIDE + uldso[ui]) = m2;           \
        }                                                                      \
    }

    const int tx = tid & 15;   // 4 output cols each
    const int ty = tid >> 4;   // 2 output rows each
    const int r0 = ty * 2;

    // Window floats 4tx+2..4tx+9 live in granules tx, tx+1, tx+2 (swizzled).
    const int offA = swzg(tx) * 4 + 2;
    const int offB = swzg(tx + 1) * 4;
    const int offC = offB + 2;
    const int offD = swzg(tx + 2) * 4;

#define CONV_STORE(TH0)                                                        \
    {                                                                          \
        float acc[CH][2][4];                                                   \
        _Pragma("unroll")                                                      \
        for (int c = 0; c < CH; ++c)                                           \
            _Pragma("unroll")                                                  \
            for (int r = 0; r < 2; ++r)                                        \
                _Pragma("unroll")                                              \
                for (int o = 0; o < 4; ++o) acc[c][r][o] = 0.f;                \
        _Pragma("unroll")                                                      \
        for (int rr = 0; rr < 6; ++rr) {                                       \
            _Pragma("unroll")                                                  \
            for (int c = 0; c < CH; ++c) {                                     \
                const float* rowb = &xs[0][0][0] + c * CSTRIDE                 \
                                    + (r0 + rr) * SWP;                         \
                const float2 p0 = *(const float2*)(rowb + offA);               \
                const float2 p1 = *(const float2*)(rowb + offB);               \
                const float2 p2 = *(const float2*)(rowb + offC);               \
                const float2 p3 = *(const float2*)(rowb + offD);               \
                const float w8[8] = {p0.x, p0.y, p1.x, p1.y,                   \
                                     p2.x, p2.y, p3.x, p3.y};                  \
                _Pragma("unroll")                                              \
                for (int i = 0; i < 5; ++i) {                                  \
                    const int r = rr - i;                                      \
                    if (r >= 0 && r < 2) {                                     \
                        _Pragma("unroll")                                      \
                        for (int j = 0; j < 5; ++j) {                          \
                            _Pragma("unroll")                                  \
                            for (int o = 0; o < 4; ++o)                        \
                                acc[c][r][o] += w8[o + j] * K[i][j];           \
                        }                                                      \
                    }                                                          \
                }                                                              \
            }                                                                  \
        }                                                                      \
        _Pragma("unroll")                                                      \
        for (int c = 0; c < CH; ++c) {                                         \
            float* ob = out + ((size_t)b * CH + c) * plane;                    \
            _Pragma("unroll")                                                  \
            for (int r = 0; r < 2; ++r) {                                      \
                const float4 vv = make_float4(acc[c][r][0], acc[c][r][1],      \
                                              acc[c][r][2], acc[c][r][3]);     \
                *(float4*)&ob[(size_t)((TH0) + r0 + r) * WW + tw0 + tx * 4] = vv; \
            }                                                                  \
        }                                                                      \
    }

    // ---- prologue: stage tile 0 ----
    STAGE_LOAD(thbase);
    STAGE_WRITE();
    __syncthreads();

    // ---- chained pipeline, single LDS buffer ----
#pragma unroll 1
    for (int t = 0; t < TPB; ++t) {
        const int th0 = thbase + t * TH;
        if (t + 1 < TPB) { STAGE_LOAD(th0 + TH); }  // issue early: hides under conv
        CONV_STORE(th0);
        __syncthreads();                             // conv reads of buffer done
        if (t + 1 < TPB) {
            STAGE_WRITE();                           // mix + write prefetched tile
            __syncthreads();                         // buffer ready for next conv
        }
    }
}

extern "C" void kernel_launch(void* const* d_in, const int* in_sizes, int n_in,
                              void* d_out, int out_size, void* d_ws, size_t ws_size,
                              hipStream_t stream) {
    const float* im   = (const float*)d_in[0];
    const float* flat = (const float*)d_in[1];
    float* out        = (float*)d_out;

    colwarp_conv_kernel<<<dim3(NWG), dim3(256), 0, stream>>>(im, flat, out);
}

// Round 10
// 101.538 us; speedup vs baseline: 1.9950x; 1.9950x over previous
//
#include <hip/hip_runtime.h>

// Problem constants (match reference)
#define NB 32
#define CH 3
#define HH 768
#define WW 768

// Tiling
#define TW 64                   // tile width
#define TH 16                   // tile height (small -> dbuf fits 4 blocks/CU)
#define SW 72                   // staged (used) width: [tw0-4, tw0+68)
#define SWP 76                  // LDS row stride (19 granules)
#define SH (TH + 4)             // 20 staged rows
#define CSTRIDE (SH * SWP)      // floats per channel plane
#define TPB 8                   // tiles per block (vertical chain, 128 rows)
#define NTC (WW / TW)           // 12
#define NTG (HH / (TH * TPB))   // 6
#define NWG (NB * NTC * NTG)    // 2304 = 9 blocks/CU, %8==0
#define UNITS (SH * (SW / 4))   // 360 float4-units per tile

typedef float v4f __attribute__((ext_vector_type(4)));  // for NT stores

// Granule swizzle within a row: kills the tx / tx+8 (delta = 32 floats) alias.
__device__ inline int swzg(int g) { return g ^ (((g >> 3) & 1) << 2); }

__global__ __launch_bounds__(256) void colwarp_conv_kernel(
    const float* __restrict__ im,
    const float* __restrict__ flat,
    float* __restrict__ out)
{
    // XCD-contiguous mapping; wid = ((b*NTG)+tg)*NTC + tc so one XCD owns
    // whole images (4 each) -> all halo sharing stays in its L2.
    const int d   = blockIdx.x;
    const int wid = (d & 7) * (NWG / 8) + (d >> 3);
    const int tc  = wid % NTC;
    const int t2  = wid / NTC;
    const int tg  = t2 % NTG;
    const int b   = t2 / NTG;
    const int tw0 = tc * TW;
    const int thbase = tg * (TPB * TH);

    __shared__ float xs[2][CH][SH][SWP];   // 36480 B -> 4 blocks/CU (LDS-capped)

    const int tid = threadIdx.x;

    // ---- per-sample params (b block-uniform -> scalar) ----
    const float* f = flat + b * 37;
    float Wm[3][3];
#pragma unroll
    for (int i = 0; i < 3; ++i)
#pragma unroll
        for (int j = 0; j < 3; ++j) Wm[i][j] = f[i * 3 + j];
    float sh3[3];
#pragma unroll
    for (int i = 0; i < 3; ++i) sh3[i] = f[9 + i];
    float K[5][5];
#pragma unroll
    for (int i = 0; i < 5; ++i)
#pragma unroll
        for (int j = 0; j < 5; ++j) K[i][j] = f[12 + i * 5 + j];
    float bias[3];
#pragma unroll
    for (int c = 0; c < 3; ++c)
        bias[c] = sh3[0]*Wm[0][c] + sh3[1]*Wm[1][c] + sh3[2]*Wm[2][c];

    const size_t plane = (size_t)HH * WW;
    const float* im0 = im + (size_t)b * CH * plane;

    // ---- this thread's staging units: u, u+256 (360 total) ----
    int ur[2], uldso[2], ugw[2];
    bool uon[2];
#pragma unroll
    for (int ui = 0; ui < 2; ++ui) {
        const int u  = tid + 256 * ui;
        const int rr = u / (SW / 4);
        const int c4 = u - rr * (SW / 4);
        ur[ui]    = rr;
        uldso[ui] = rr * SWP + swzg(c4) * 4;
        ugw[ui]   = tw0 - 4 + c4 * 4;
        uon[ui]   = (u < UNITS);
    }

    float4 vld[2][CH];   // in-flight raw loads (24 floats)
    bool vok[2];

#define STAGE_LOAD(TH0)                                                        \
    _Pragma("unroll")                                                          \
    for (int ui = 0; ui < 2; ++ui) {                                           \
        const int gh = (TH0) + ur[ui] - 2;                                     \
        const bool ok = uon[ui] && ((unsigned)gh < (unsigned)HH)               \
                                && ((unsigned)ugw[ui] < (unsigned)WW);         \
        vok[ui] = ok;                                                          \
        if (ok) {                                                              \
            const size_t off = (size_t)gh * WW + ugw[ui];                      \
            vld[ui][0] = *(const float4*)(im0 + off);                          \
            vld[ui][1] = *(const float4*)(im0 + plane + off);                  \
            vld[ui][2] = *(const float4*)(im0 + 2 * plane + off);              \
        }                                                                      \
    }

#define STAGE_WRITE(BUFP)                                                      \
    _Pragma("unroll")                                                          \
    for (int ui = 0; ui < 2; ++ui) {                                           \
        if (uon[ui]) {                                                         \
            float4 m0 = make_float4(0.f, 0.f, 0.f, 0.f), m1 = m0, m2 = m0;     \
            if (vok[ui]) {                                                     \
                const float4 a0 = vld[ui][0], a1 = vld[ui][1], a2 = vld[ui][2];\
                m0.x = a0.x*Wm[0][0] + a1.x*Wm[1][0] + a2.x*Wm[2][0] + bias[0];\
                m0.y = a0.y*Wm[0][0] + a1.y*Wm[1][0] + a2.y*Wm[2][0] + bias[0];\
                m0.z = a0.z*Wm[0][0] + a1.z*Wm[1][0] + a2.z*Wm[2][0] + bias[0];\
                m0.w = a0.w*Wm[0][0] + a1.w*Wm[1][0] + a2.w*Wm[2][0] + bias[0];\
                m1.x = a0.x*Wm[0][1] + a1.x*Wm[1][1] + a2.x*Wm[2][1] + bias[1];\
                m1.y = a0.y*Wm[0][1] + a1.y*Wm[1][1] + a2.y*Wm[2][1] + bias[1];\
                m1.z = a0.z*Wm[0][1] + a1.z*Wm[1][1] + a2.z*Wm[2][1] + bias[1];\
                m1.w = a0.w*Wm[0][1] + a1.w*Wm[1][1] + a2.w*Wm[2][1] + bias[1];\
                m2.x = a0.x*Wm[0][2] + a1.x*Wm[1][2] + a2.x*Wm[2][2] + bias[2];\
                m2.y = a0.y*Wm[0][2] + a1.y*Wm[1][2] + a2.y*Wm[2][2] + bias[2];\
                m2.z = a0.z*Wm[0][2] + a1.z*Wm[1][2] + a2.z*Wm[2][2] + bias[2];\
                m2.w = a0.w*Wm[0][2] + a1.w*Wm[1][2] + a2.w*Wm[2][2] + bias[2];\
            }                                                                  \
            *(float4*)((BUFP) + 0 * CSTRIDE + uldso[ui]) = m0;                 \
            *(float4*)((BUFP) + 1 * CSTRIDE + uldso[ui]) = m1;                 \
            *(float4*)((BUFP) + 2 * CSTRIDE + uldso[ui]) = m2;                 \
        }                                                                      \
    }

    const int tx = tid & 15;   // 4 output cols
    const int ty = tid >> 4;   // 1 output row (= r0)
    const int r0 = ty;

    // Window floats 4tx+2..4tx+9 live in granules tx, tx+1, tx+2 (swizzled).
    const int offA = swzg(tx) * 4 + 2;
    const int offB = swzg(tx + 1) * 4;
    const int offC = offB + 2;
    const int offD = swzg(tx + 2) * 4;

#define CONV_STORE(BUFP, TH0)                                                  \
    {                                                                          \
        float acc[CH][4];                                                      \
        _Pragma("unroll")                                                      \
        for (int c = 0; c < CH; ++c)                                           \
            _Pragma("unroll")                                                  \
            for (int o = 0; o < 4; ++o) acc[c][o] = 0.f;                       \
        _Pragma("unroll")                                                      \
        for (int rr = 0; rr < 5; ++rr) {                                       \
            _Pragma("unroll")                                                  \
            for (int c = 0; c < CH; ++c) {                                     \
                const float* rowb = (BUFP) + c * CSTRIDE + (r0 + rr) * SWP;    \
                const float2 p0 = *(const float2*)(rowb + offA);               \
                const float2 p1 = *(const float2*)(rowb + offB);               \
                const float2 p2 = *(const float2*)(rowb + offC);               \
                const float2 p3 = *(const float2*)(rowb + offD);               \
                const float w8[8] = {p0.x, p0.y, p1.x, p1.y,                   \
                                     p2.x, p2.y, p3.x, p3.y};                  \
                _Pragma("unroll")                                              \
                for (int j = 0; j < 5; ++j) {                                  \
                    _Pragma("unroll")                                          \
                    for (int o = 0; o < 4; ++o)                                \
                        acc[c][o] += w8[o + j] * K[rr][j];                     \
                }                                                              \
            }                                                                  \
        }                                                                      \
        _Pragma("unroll")                                                      \
        for (int c = 0; c < CH; ++c) {                                         \
            float* ob = out + ((size_t)b * CH + c) * plane;                    \
            v4f vv = {acc[c][0], acc[c][1], acc[c][2], acc[c][3]};             \
            __builtin_nontemporal_store(vv,                                    \
                (v4f*)&ob[(size_t)((TH0) + r0) * WW + tw0 + tx * 4]);          \
        }                                                                      \
    }

    // ---- prologue: stage tile 0 into buffer 0 ----
    STAGE_LOAD(thbase);
    STAGE_WRITE(&xs[0][0][0][0]);
    __syncthreads();

    // ---- chained double-buffer pipeline: 1 barrier per tile ----
#pragma unroll 1
    for (int t = 0; t < TPB; ++t) {
        const int th0 = thbase + t * TH;
        float* cur = &xs[t & 1][0][0][0];
        float* nxt = &xs[(t & 1) ^ 1][0][0][0];
        if (t + 1 < TPB) { STAGE_LOAD(th0 + TH); }   // issue loads early
        CONV_STORE(cur, th0);                         // compute hides HBM latency
        if (t + 1 < TPB) { STAGE_WRITE(nxt); }        // mix + write other buffer
        __syncthreads();                              // cur fully read, nxt ready
    }
}

extern "C" void kernel_launch(void* const* d_in, const int* in_sizes, int n_in,
                              void* d_out, int out_size, void* d_ws, size_t ws_size,
                              hipStream_t stream) {
    const float* im   = (const float*)d_in[0];
    const float* flat = (const float*)d_in[1];
    float* out        = (float*)d_out;

    colwarp_conv_kernel<<<dim3(NWG), dim3(256), 0, stream>>>(im, flat, out);
}

// Round 11
// 81.104 us; speedup vs baseline: 2.4976x; 1.2520x over previous
//
#include <hip/hip_runtime.h>

// Problem constants (match reference)
#define NB 32
#define CH 3
#define HH 768
#define WW 768

// Tiling
#define TW 64                   // tile width
#define TH 16                   // tile height (small -> dbuf fits 4 blocks/CU)
#define SW 72                   // staged (used) width: [tw0-4, tw0+68)
#define SWP 76                  // LDS row stride (19 granules)
#define SH (TH + 4)             // 20 staged rows
#define CSTRIDE (SH * SWP)      // floats per channel plane
#define TPB 8                   // tiles per block (vertical chain, 128 rows)
#define NTC (WW / TW)           // 12
#define NTG (HH / (TH * TPB))   // 6
#define NWG (NB * NTC * NTG)    // 2304 = 9 blocks/CU, %8==0
#define UNITS (SH * (SW / 4))   // 360 float4-units per tile

typedef float v4f __attribute__((ext_vector_type(4)));  // for NT stores

// Pair-swap swizzle: logical within-row float f lives at physical
// f ^ (((f>>5)&1)<<1). Granule addresses unchanged; granules 8..15 store
// their two float2 halves swapped. For every conv read position
// s in {4tx+2,4tx+4,4tx+6,4tx+8}, the 16 tx-lanes then cover all 32 banks
// exactly once -> conflict-free (granule-level swizzles are provably 2-way).
__device__ inline int pswz(int s) { return s ^ (((s >> 5) & 1) << 1); }

__global__ __launch_bounds__(256) void colwarp_conv_kernel(
    const float* __restrict__ im,
    const float* __restrict__ flat,
    float* __restrict__ out)
{
    // XCD-contiguous mapping; one XCD owns whole images (4 each).
    const int d   = blockIdx.x;
    const int wid = (d & 7) * (NWG / 8) + (d >> 3);
    const int tc  = wid % NTC;
    const int t2  = wid / NTC;
    const int tg  = t2 % NTG;
    const int b   = t2 / NTG;
    const int tw0 = tc * TW;
    const int thbase = tg * (TPB * TH);

    __shared__ float xs[2][CH][SH][SWP];   // 36480 B -> 4 blocks/CU (LDS-capped)

    const int tid = threadIdx.x;

    // ---- per-sample params (b block-uniform -> scalar) ----
    const float* f = flat + b * 37;
    float Wm[3][3];
#pragma unroll
    for (int i = 0; i < 3; ++i)
#pragma unroll
        for (int j = 0; j < 3; ++j) Wm[i][j] = f[i * 3 + j];
    float sh3[3];
#pragma unroll
    for (int i = 0; i < 3; ++i) sh3[i] = f[9 + i];
    float K[5][5];
#pragma unroll
    for (int i = 0; i < 5; ++i)
#pragma unroll
        for (int j = 0; j < 5; ++j) K[i][j] = f[12 + i * 5 + j];
    float bias[3];
#pragma unroll
    for (int c = 0; c < 3; ++c)
        bias[c] = sh3[0]*Wm[0][c] + sh3[1]*Wm[1][c] + sh3[2]*Wm[2][c];

    const size_t plane = (size_t)HH * WW;
    const float* im0 = im + (size_t)b * CH * plane;

    // ---- this thread's staging units: u, u+256 (360 total) ----
    int ur[2], uldso[2], ugw[2];
    bool uon[2], uswap[2];
#pragma unroll
    for (int ui = 0; ui < 2; ++ui) {
        const int u  = tid + 256 * ui;
        const int rr = u / (SW / 4);
        const int c4 = u - rr * (SW / 4);     // granule 0..17
        ur[ui]    = rr;
        uldso[ui] = rr * SWP + c4 * 4;        // linear granule address
        ugw[ui]   = tw0 - 4 + c4 * 4;
        uon[ui]   = (u < UNITS);
        uswap[ui] = ((c4 >> 3) & 1) != 0;     // granules 8..15: swap halves
    }

    float4 vld[2][CH];   // in-flight raw loads (24 floats)
    bool vok[2];

#define STAGE_LOAD(TH0)                                                        \
    _Pragma("unroll")                                                          \
    for (int ui = 0; ui < 2; ++ui) {                                           \
        const int gh = (TH0) + ur[ui] - 2;                                     \
        const bool ok = uon[ui] && ((unsigned)gh < (unsigned)HH)               \
                                && ((unsigned)ugw[ui] < (unsigned)WW);         \
        vok[ui] = ok;                                                          \
        if (ok) {                                                              \
            const size_t off = (size_t)gh * WW + ugw[ui];                      \
            vld[ui][0] = *(const float4*)(im0 + off);                          \
            vld[ui][1] = *(const float4*)(im0 + plane + off);                  \
            vld[ui][2] = *(const float4*)(im0 + 2 * plane + off);              \
        }                                                                      \
    }

#define STAGE_WRITE(BUFP)                                                      \
    _Pragma("unroll")                                                          \
    for (int ui = 0; ui < 2; ++ui) {                                           \
        if (uon[ui]) {                                                         \
            float4 m0 = make_float4(0.f, 0.f, 0.f, 0.f), m1 = m0, m2 = m0;     \
            if (vok[ui]) {                                                     \
                const float4 a0 = vld[ui][0], a1 = vld[ui][1], a2 = vld[ui][2];\
                m0.x = a0.x*Wm[0][0] + a1.x*Wm[1][0] + a2.x*Wm[2][0] + bias[0];\
                m0.y = a0.y*Wm[0][0] + a1.y*Wm[1][0] + a2.y*Wm[2][0] + bias[0];\
                m0.z = a0.z*Wm[0][0] + a1.z*Wm[1][0] + a2.z*Wm[2][0] + bias[0];\
                m0.w = a0.w*Wm[0][0] + a1.w*Wm[1][0] + a2.w*Wm[2][0] + bias[0];\
                m1.x = a0.x*Wm[0][1] + a1.x*Wm[1][1] + a2.x*Wm[2][1] + bias[1];\
                m1.y = a0.y*Wm[0][1] + a1.y*Wm[1][1] + a2.y*Wm[2][1] + bias[1];\
                m1.z = a0.z*Wm[0][1] + a1.z*Wm[1][1] + a2.z*Wm[2][1] + bias[1];\
                m1.w = a0.w*Wm[0][1] + a1.w*Wm[1][1] + a2.w*Wm[2][1] + bias[1];\
                m2.x = a0.x*Wm[0][2] + a1.x*Wm[1][2] + a2.x*Wm[2][2] + bias[2];\
                m2.y = a0.y*Wm[0][2] + a1.y*Wm[1][2] + a2.y*Wm[2][2] + bias[2];\
                m2.z = a0.z*Wm[0][2] + a1.z*Wm[1][2] + a2.z*Wm[2][2] + bias[2];\
                m2.w = a0.w*Wm[0][2] + a1.w*Wm[1][2] + a2.w*Wm[2][2] + bias[2];\
            }                                                                  \
            const bool sw = uswap[ui];                                         \
            const float4 w0 = sw ? make_float4(m0.z,m0.w,m0.x,m0.y) : m0;      \
            const float4 w1 = sw ? make_float4(m1.z,m1.w,m1.x,m1.y) : m1;      \
            const float4 w2 = sw ? make_float4(m2.z,m2.w,m2.x,m2.y) : m2;      \
            *(float4*)((BUFP) + 0 * CSTRIDE + uldso[ui]) = w0;                 \
            *(float4*)((BUFP) + 1 * CSTRIDE + uldso[ui]) = w1;                 \
            *(float4*)((BUFP) + 2 * CSTRIDE + uldso[ui]) = w2;                 \
        }                                                                      \
    }

    const int tx = tid & 15;   // 4 output cols
    const int ty = tid >> 4;   // 1 output row (= r0)
    const int r0 = ty;

    // Conv window logical floats 4tx+2..4tx+9 read as 4 float2 pairs at
    // physical (pair-swizzled) offsets:
    const int offA = pswz(4 * tx + 2);
    const int offB = pswz(4 * tx + 4);
    const int offC = pswz(4 * tx + 6);
    const int offD = pswz(4 * tx + 8);

#define CONV_STORE(BUFP, TH0)                                                  \
    {                                                                          \
        float acc[CH][4];                                                      \
        _Pragma("unroll")                                                      \
        for (int c = 0; c < CH; ++c)                                           \
            _Pragma("unroll")                                                  \
            for (int o = 0; o < 4; ++o) acc[c][o] = 0.f;                       \
        _Pragma("unroll")                                                      \
        for (int rr = 0; rr < 5; ++rr) {                                       \
            _Pragma("unroll")                                                  \
            for (int c = 0; c < CH; ++c) {                                     \
                const float* rowb = (BUFP) + c * CSTRIDE + (r0 + rr) * SWP;    \
                const float2 p0 = *(const float2*)(rowb + offA);               \
                const float2 p1 = *(const float2*)(rowb + offB);               \
                const float2 p2 = *(const float2*)(rowb + offC);               \
                const float2 p3 = *(const float2*)(rowb + offD);               \
                const float w8[8] = {p0.x, p0.y, p1.x, p1.y,                   \
                                     p2.x, p2.y, p3.x, p3.y};                  \
                _Pragma("unroll")                                              \
                for (int j = 0; j < 5; ++j) {                                  \
                    _Pragma("unroll")                                          \
                    for (int o = 0; o < 4; ++o)                                \
                        acc[c][o] += w8[o + j] * K[rr][j];                     \
                }                                                              \
            }                                                                  \
        }                                                                      \
        _Pragma("unroll")                                                      \
        for (int c = 0; c < CH; ++c) {                                         \
            float* ob = out + ((size_t)b * CH + c) * plane;                    \
            v4f vv = {acc[c][0], acc[c][1], acc[c][2], acc[c][3]};             \
            __builtin_nontemporal_store(vv,                                    \
                (v4f*)&ob[(size_t)((TH0) + r0) * WW + tw0 + tx * 4]);          \
        }                                                                      \
    }

    // ---- prologue: stage tile 0 into buffer 0 ----
    STAGE_LOAD(thbase);
    STAGE_WRITE(&xs[0][0][0][0]);
    __syncthreads();

    // ---- chained double-buffer pipeline: 1 barrier per tile ----
#pragma unroll 1
    for (int t = 0; t < TPB; ++t) {
        const int th0 = thbase + t * TH;
        float* cur = &xs[t & 1][0][0][0];
        float* nxt = &xs[(t & 1) ^ 1][0][0][0];
        if (t + 1 < TPB) { STAGE_LOAD(th0 + TH); }   // issue loads early
        CONV_STORE(cur, th0);                         // compute hides HBM latency
        if (t + 1 < TPB) { STAGE_WRITE(nxt); }        // mix + write other buffer
        __syncthreads();                              // cur fully read, nxt ready
    }
}

extern "C" void kernel_launch(void* const* d_in, const int* in_sizes, int n_in,
                              void* d_out, int out_size, void* d_ws, size_t ws_size,
                              hipStream_t stream) {
    const float* im   = (const float*)d_in[0];
    const float* flat = (const float*)d_in[1];
    float* out        = (float*)d_out;

    colwarp_conv_kernel<<<dim3(NWG), dim3(256), 0, stream>>>(im, flat, out);
}

// Round 12
// 80.990 us; speedup vs baseline: 2.5011x; 1.0014x over previous
//
#include <hip/hip_runtime.h>

// Problem constants (match reference)
#define NB 32
#define CH 3
#define HH 768
#define WW 768

// Tiling
#define TW 64                   // tile width
#define TH 16                   // tile height
#define SW 72                   // staged (used) width: [tw0-4, tw0+68)
#define SWP 76                  // LDS row stride
#define SH (TH + 4)             // 20 staged rows
#define CSTRIDE (SH * SWP)      // floats per channel plane
#define TPB 8                   // tiles per block (vertical chain, 128 rows)
#define NTC (WW / TW)           // 12
#define NTG (HH / (TH * TPB))   // 6
#define NWG (NB * NTC * NTG)    // 2304, %8==0
#define UNITS (SH * (SW / 4))   // 360 float4-units per tile

typedef float v4f __attribute__((ext_vector_type(4)));  // for NT stores

// Pair-swap swizzle: logical within-row float f lives at physical
// f ^ (((f>>5)&1)<<1). Conv reads at s in {4tx+2,4tx+4,4tx+6,4tx+8} then
// cover all 32 banks exactly once across the 16 tx lanes -> conflict-free.
__device__ inline int pswz(int s) { return s ^ (((s >> 5) & 1) << 1); }

__global__ __launch_bounds__(256) void colwarp_conv_kernel(
    const float* __restrict__ im,
    const float* __restrict__ flat,
    float* __restrict__ out)
{
    // XCD-contiguous mapping; one XCD owns whole images (4 each).
    const int d   = blockIdx.x;
    const int wid = (d & 7) * (NWG / 8) + (d >> 3);
    const int tc  = wid % NTC;
    const int t2  = wid / NTC;
    const int tg  = t2 % NTG;
    const int b   = t2 / NTG;
    const int tw0 = tc * TW;
    const int thbase = tg * (TPB * TH);

    // SINGLE buffer: 3*20*76*4 = 18240 B -> 8 blocks/CU (32 waves/CU)
    __shared__ float xs[CH][SH][SWP];

    const int tid = threadIdx.x;

    // ---- per-sample params (b block-uniform -> scalar) ----
    const float* f = flat + b * 37;
    float Wm[3][3];
#pragma unroll
    for (int i = 0; i < 3; ++i)
#pragma unroll
        for (int j = 0; j < 3; ++j) Wm[i][j] = f[i * 3 + j];
    float sh3[3];
#pragma unroll
    for (int i = 0; i < 3; ++i) sh3[i] = f[9 + i];
    float K[5][5];
#pragma unroll
    for (int i = 0; i < 5; ++i)
#pragma unroll
        for (int j = 0; j < 5; ++j) K[i][j] = f[12 + i * 5 + j];
    float bias[3];
#pragma unroll
    for (int c = 0; c < 3; ++c)
        bias[c] = sh3[0]*Wm[0][c] + sh3[1]*Wm[1][c] + sh3[2]*Wm[2][c];

    const size_t plane = (size_t)HH * WW;
    const float* im0 = im + (size_t)b * CH * plane;

    // ---- this thread's staging units: u, u+256 (360 total) ----
    int ur[2], uldso[2], ugw[2];
    bool uon[2], uswap[2];
#pragma unroll
    for (int ui = 0; ui < 2; ++ui) {
        const int u  = tid + 256 * ui;
        const int rr = u / (SW / 4);
        const int c4 = u - rr * (SW / 4);     // granule 0..17
        ur[ui]    = rr;
        uldso[ui] = rr * SWP + c4 * 4;        // linear granule address
        ugw[ui]   = tw0 - 4 + c4 * 4;
        uon[ui]   = (u < UNITS);
        uswap[ui] = ((c4 >> 3) & 1) != 0;     // granules 8..15: swap halves
    }

    float4 vld[2][CH];   // in-flight raw loads (24 floats)
    bool vok[2];

#define STAGE_LOAD(TH0)                                                        \
    _Pragma("unroll")                                                          \
    for (int ui = 0; ui < 2; ++ui) {                                           \
        const int gh = (TH0) + ur[ui] - 2;                                     \
        const bool ok = uon[ui] && ((unsigned)gh < (unsigned)HH)               \
                                && ((unsigned)ugw[ui] < (unsigned)WW);         \
        vok[ui] = ok;                                                          \
        if (ok) {                                                              \
            const size_t off = (size_t)gh * WW + ugw[ui];                      \
            vld[ui][0] = *(const float4*)(im0 + off);                          \
            vld[ui][1] = *(const float4*)(im0 + plane + off);                  \
            vld[ui][2] = *(const float4*)(im0 + 2 * plane + off);              \
        }                                                                      \
    }

#define STAGE_WRITE(BUFP)                                                      \
    _Pragma("unroll")                                                          \
    for (int ui = 0; ui < 2; ++ui) {                                           \
        if (uon[ui]) {                                                         \
            float4 m0 = make_float4(0.f, 0.f, 0.f, 0.f), m1 = m0, m2 = m0;     \
            if (vok[ui]) {                                                     \
                const float4 a0 = vld[ui][0], a1 = vld[ui][1], a2 = vld[ui][2];\
                m0.x = a0.x*Wm[0][0] + a1.x*Wm[1][0] + a2.x*Wm[2][0] + bias[0];\
                m0.y = a0.y*Wm[0][0] + a1.y*Wm[1][0] + a2.y*Wm[2][0] + bias[0];\
                m0.z = a0.z*Wm[0][0] + a1.z*Wm[1][0] + a2.z*Wm[2][0] + bias[0];\
                m0.w = a0.w*Wm[0][0] + a1.w*Wm[1][0] + a2.w*Wm[2][0] + bias[0];\
                m1.x = a0.x*Wm[0][1] + a1.x*Wm[1][1] + a2.x*Wm[2][1] + bias[1];\
                m1.y = a0.y*Wm[0][1] + a1.y*Wm[1][1] + a2.y*Wm[2][1] + bias[1];\
                m1.z = a0.z*Wm[0][1] + a1.z*Wm[1][1] + a2.z*Wm[2][1] + bias[1];\
                m1.w = a0.w*Wm[0][1] + a1.w*Wm[1][1] + a2.w*Wm[2][1] + bias[1];\
                m2.x = a0.x*Wm[0][2] + a1.x*Wm[1][2] + a2.x*Wm[2][2] + bias[2];\
                m2.y = a0.y*Wm[0][2] + a1.y*Wm[1][2] + a2.y*Wm[2][2] + bias[2];\
                m2.z = a0.z*Wm[0][2] + a1.z*Wm[1][2] + a2.z*Wm[2][2] + bias[2];\
                m2.w = a0.w*Wm[0][2] + a1.w*Wm[1][2] + a2.w*Wm[2][2] + bias[2];\
            }                                                                  \
            const bool sw = uswap[ui];                                         \
            const float4 w0 = sw ? make_float4(m0.z,m0.w,m0.x,m0.y) : m0;      \
            const float4 w1 = sw ? make_float4(m1.z,m1.w,m1.x,m1.y) : m1;      \
            const float4 w2 = sw ? make_float4(m2.z,m2.w,m2.x,m2.y) : m2;      \
            *(float4*)((BUFP) + 0 * CSTRIDE + uldso[ui]) = w0;                 \
            *(float4*)((BUFP) + 1 * CSTRIDE + uldso[ui]) = w1;                 \
            *(float4*)((BUFP) + 2 * CSTRIDE + uldso[ui]) = w2;                 \
        }                                                                      \
    }

    const int tx = tid & 15;   // 4 output cols
    const int ty = tid >> 4;   // 1 output row (= r0)
    const int r0 = ty;

    // Conv window logical floats 4tx+2..4tx+9 as 4 float2 pairs (pair-swizzled):
    const int offA = pswz(4 * tx + 2);
    const int offB = pswz(4 * tx + 4);
    const int offC = pswz(4 * tx + 6);
    const int offD = pswz(4 * tx + 8);

#define CONV_STORE(BUFP, TH0)                                                  \
    {                                                                          \
        float acc[CH][4];                                                      \
        _Pragma("unroll")                                                      \
        for (int c = 0; c < CH; ++c)                                           \
            _Pragma("unroll")                                                  \
            for (int o = 0; o < 4; ++o) acc[c][o] = 0.f;                       \
        _Pragma("unroll")                                                      \
        for (int rr = 0; rr < 5; ++rr) {                                       \
            _Pragma("unroll")                                                  \
            for (int c = 0; c < CH; ++c) {                                     \
                const float* rowb = (BUFP) + c * CSTRIDE + (r0 + rr) * SWP;    \
                const float2 p0 = *(const float2*)(rowb + offA);               \
                const float2 p1 = *(const float2*)(rowb + offB);               \
                const float2 p2 = *(const float2*)(rowb + offC);               \
                const float2 p3 = *(const float2*)(rowb + offD);               \
                const float w8[8] = {p0.x, p0.y, p1.x, p1.y,                   \
                                     p2.x, p2.y, p3.x, p3.y};                  \
                _Pragma("unroll")                                              \
                for (int j = 0; j < 5; ++j) {                                  \
                    _Pragma("unroll")                                          \
                    for (int o = 0; o < 4; ++o)                                \
                        acc[c][o] += w8[o + j] * K[rr][j];                     \
                }                                                              \
            }                                                                  \
        }                                                                      \
        _Pragma("unroll")                                                      \
        for (int c = 0; c < CH; ++c) {                                         \
            float* ob = out + ((size_t)b * CH + c) * plane;                    \
            v4f vv = {acc[c][0], acc[c][1], acc[c][2], acc[c][3]};             \
            __builtin_nontemporal_store(vv,                                    \
                (v4f*)&ob[(size_t)((TH0) + r0) * WW + tw0 + tx * 4]);          \
        }                                                                      \
    }

    // ---- prologue: stage tile 0 ----
    STAGE_LOAD(thbase);
    STAGE_WRITE(&xs[0][0][0]);
    __syncthreads();

    // ---- chained single-buffer pipeline: load-early, write-late ----
#pragma unroll 1
    for (int t = 0; t < TPB; ++t) {
        const int th0 = thbase + t * TH;
        if (t + 1 < TPB) { STAGE_LOAD(th0 + TH); }   // HBM issue hides under conv
        CONV_STORE(&xs[0][0][0], th0);
        __syncthreads();                              // all reads of buffer done
        if (t + 1 < TPB) {
            STAGE_WRITE(&xs[0][0][0]);                // mix + write next tile
            __syncthreads();                          // buffer ready
        }
    }
}

extern "C" void kernel_launch(void* const* d_in, const int* in_sizes, int n_in,
                              void* d_out, int out_size, void* d_ws, size_t ws_size,
                              hipStream_t stream) {
    const float* im   = (const float*)d_in[0];
    const float* flat = (const float*)d_in[1];
    float* out        = (float*)d_out;

    colwarp_conv_kernel<<<dim3(NWG), dim3(256), 0, stream>>>(im, flat, out);
}